// Round 4
// baseline (2561.297 us; speedup 1.0000x reference)
//
#include <hip/hip_runtime.h>
#include <hip/hip_cooperative_groups.h>

// RNN_73701638799445: 2-layer tanh RNN.
// v3: persistent cooperative recurrence kernel (replaces 65 phase launches).
//   192 blocks = 64 L0 + 64 L1a + 64 L1b; each block: 16 n-cols x all 64 batch rows;
//   weight slice (16x2048 bf16 hi|lo = 64KB) preloaded once into LDS (XOR-swizzled),
//   reused across all timesteps. Software pipeline: phase p does
//     L0 : h0_p    = tanh(U0[p] + h0_{p-1} @ Wh0^T)
//     L1a: P_{p-1} = h0_{p-1} @ W1^T                (f32 partial)
//     L1b: h1_{p-2}= tanh(P_{p-2} + h1_{p-3} @ Wh1^T + b1)
//   -> 1 grid.sync() per phase, 66 phases. Same split-bf16 3-term math as v2.
// Decoder/U0 GEMM unchanged from v2 (XCD n-band swizzle, FETCH 360->88MB verified).

#define S_LEN 64
#define BATCH 64
#define HID   1024
#define VOCAB 10000
#define VPAD  10240           // 80 * 128
#define SB    4096            // S_LEN * BATCH
#define SBV   40960000        // SB * VOCAB

typedef __attribute__((ext_vector_type(4))) float  f32x4;
typedef __attribute__((ext_vector_type(8))) __bf16 bf16x8;

__device__ inline unsigned short f2bf(float x) {
  union { float f; unsigned int u; } v; v.f = x;
  unsigned int r = v.u + 0x7fffu + ((v.u >> 16) & 1u);   // RNE
  return (unsigned short)(r >> 16);
}
__device__ inline float bf2f(unsigned short s) {
  union { unsigned int u; float f; } v; v.u = ((unsigned int)s) << 16;
  return v.f;
}

// ---------------- prep kernels ----------------

// x[s,b,:] = emb[inputs[s,b]] -> bf16, 4 elems/thread
__global__ __launch_bounds__(256) void prep_x(
    const int* __restrict__ inputs, const float* __restrict__ emb,
    unsigned short* __restrict__ Xbf) {
  int i = blockIdx.x * 256 + threadIdx.x;       // SB*HID/4 threads
  int row = i >> 8;
  int c4  = (i & 255) * 4;
  int tok = inputs[row];
  const float4 v = *reinterpret_cast<const float4*>(emb + (size_t)tok * HID + c4);
  unsigned short* o = Xbf + (size_t)row * HID + c4;
  o[0] = f2bf(v.x); o[1] = f2bf(v.y); o[2] = f2bf(v.z); o[3] = f2bf(v.w);
}

// W0 -> bf16; Wh0 -> B0c [hi|lo] (row 2048); W1 -> B1a [hi|lo]; Wh1 -> B1b [hi|lo]
__global__ __launch_bounds__(256) void prep_w(
    const float* __restrict__ W0, const float* __restrict__ Wh0,
    const float* __restrict__ W1, const float* __restrict__ Wh1,
    unsigned short* __restrict__ W0bf, unsigned short* __restrict__ B0c,
    unsigned short* __restrict__ B1a, unsigned short* __restrict__ B1b) {
  int id = blockIdx.x * 256 + threadIdx.x;      // HID*HID threads
  int n = id >> 10, k = id & 1023;
  W0bf[id] = f2bf(W0[id]);
  size_t base = (size_t)n * 2048 + k;
  {
    float w = Wh0[id];
    unsigned short hi = f2bf(w);
    B0c[base] = hi; B0c[base + 1024] = f2bf(w - bf2f(hi));
  }
  {
    float w = W1[id];
    unsigned short hi = f2bf(w);
    B1a[base] = hi; B1a[base + 1024] = f2bf(w - bf2f(hi));
  }
  {
    float w = Wh1[id];
    unsigned short hi = f2bf(w);
    B1b[base] = hi; B1b[base + 1024] = f2bf(w - bf2f(hi));
  }
}

// Wd -> bf16 padded to VPAD rows (pad rows = 0); bd -> padded f32
__global__ __launch_bounds__(256) void prep_wd(
    const float* __restrict__ Wd, const float* __restrict__ bd,
    unsigned short* __restrict__ Wdbf, float* __restrict__ bdp) {
  int id = blockIdx.x * 256 + threadIdx.x;      // VPAD*1024 threads
  int row = id >> 10;
  Wdbf[id] = (row < VOCAB) ? f2bf(Wd[id]) : (unsigned short)0;
  if (id < VPAD) bdp[id] = (id < VOCAB) ? bd[id] : 0.0f;
}

// init state buffers: A0x = [h0hi|h0lo] rows 2048, A1x = [h1hi|h1lo] rows 2048
__global__ __launch_bounds__(256) void prep_h(
    const float* __restrict__ hidden,
    unsigned short* __restrict__ A0x, unsigned short* __restrict__ A1x) {
  int id = blockIdx.x * 256 + threadIdx.x;      // BATCH*HID threads
  int b = id >> 10, n = id & 1023;
  float h0 = hidden[id];
  float h1 = hidden[BATCH * HID + id];
  unsigned short h0hi = f2bf(h0), h1hi = f2bf(h1);
  size_t o = (size_t)b * 2048 + n;
  A0x[o] = h0hi; A0x[o + 1024] = f2bf(h0 - bf2f(h0hi));
  A1x[o] = h1hi; A1x[o + 1024] = f2bf(h1 - bf2f(h1hi));
}

// ---------------- big bf16 GEMM (unchanged from v2) ----------------
__global__ __launch_bounds__(256) void gemm_bt_bias(
    const unsigned short* __restrict__ A, const unsigned short* __restrict__ B,
    const float* __restrict__ bias, float* __restrict__ C,
    int K, int N, int ldc) {
  unsigned bx = blockIdx.x, by = blockIdx.y;
  if ((gridDim.x & 7u) == 0u) {
    const unsigned lin = blockIdx.x + gridDim.x * blockIdx.y;
    const unsigned xpx = gridDim.x >> 3;
    const unsigned xcd = lin & 7u;
    const unsigned idx = lin >> 3;
    bx = xcd * xpx + idx % xpx;
    by = idx / xpx;
  }
  const int m0 = by * 128;
  const int n0 = bx * 128;
  __shared__ __align__(16) unsigned short As[128 * 64];
  __shared__ __align__(16) unsigned short Bs[128 * 64];
  const int tid = threadIdx.x;
  const int lane = tid & 63, w = tid >> 6;
  const int wm = w >> 1, wn = w & 1;
  f32x4 acc[4][4] = {};
  for (int k0 = 0; k0 < K; k0 += 64) {
#pragma unroll
    for (int i = 0; i < 4; ++i) {
      int off = i * 256 + tid;
      int row = off >> 3;
      int c8  = off & 7;
      __builtin_amdgcn_global_load_lds(
          (const __attribute__((address_space(1))) unsigned int*)(const void*)
              (A + (size_t)(m0 + row) * K + k0 + c8 * 8),
          (__attribute__((address_space(3))) unsigned int*)(void*)(As + (size_t)off * 8),
          16, 0, 0);
      __builtin_amdgcn_global_load_lds(
          (const __attribute__((address_space(1))) unsigned int*)(const void*)
              (B + (size_t)(n0 + row) * K + k0 + c8 * 8),
          (__attribute__((address_space(3))) unsigned int*)(void*)(Bs + (size_t)off * 8),
          16, 0, 0);
    }
    __syncthreads();
#pragma unroll
    for (int kk = 0; kk < 64; kk += 32) {
      bf16x8 af[4], bfr[4];
#pragma unroll
      for (int f = 0; f < 4; ++f) {
        int ar = wm * 64 + f * 16 + (lane & 15);
        int ac = kk + (lane >> 4) * 8;
        af[f]  = *reinterpret_cast<const bf16x8*>(&As[ar * 64 + ac]);
        int br = wn * 64 + f * 16 + (lane & 15);
        bfr[f] = *reinterpret_cast<const bf16x8*>(&Bs[br * 64 + ac]);
      }
#pragma unroll
      for (int i = 0; i < 4; ++i)
#pragma unroll
        for (int j = 0; j < 4; ++j)
          acc[i][j] = __builtin_amdgcn_mfma_f32_16x16x32_bf16(af[i], bfr[j], acc[i][j], 0, 0, 0);
    }
    __syncthreads();
  }
  const int rbase = (lane >> 4) * 4;
  const int cbase = lane & 15;
#pragma unroll
  for (int i = 0; i < 4; ++i) {
#pragma unroll
    for (int j = 0; j < 4; ++j) {
      int col = n0 + wn * 64 + j * 16 + cbase;
      if (col < N) {
        float bv = bias[col];
#pragma unroll
        for (int r = 0; r < 4; ++r) {
          int row = m0 + wm * 64 + i * 16 + rbase + r;
          C[(size_t)row * ldc + col] = acc[i][j][r] + bv;
        }
      }
    }
  }
}

// ---------------- persistent recurrence kernel ----------------
// grid = 192 blocks x 256 threads, cooperative. type = bid>>6: 0=L0, 1=L1a, 2=L1b.
// Each block: output tile [64 batch rows x 16 cols], weights LDS-resident.
// Buffers ping-pong on phase parity pm:
//   L0 : reads A0[pm],  writes A0[1-pm]          (h0, [hi|lo] 2048/row)
//   L1a: reads A0[pm],  writes P[1-pm]           (f32 64x1024)
//   L1b: reads A1[pm]+P[pm], writes A1[1-pm], H1bf[p-2]
__global__ __launch_bounds__(256, 2) void rnn_persist(
    const unsigned short* __restrict__ B0c,
    const unsigned short* __restrict__ B1a,
    const unsigned short* __restrict__ B1b,
    const float* __restrict__ U0,
    const float* __restrict__ b1,
    unsigned short* __restrict__ A0x, unsigned short* __restrict__ A0y,
    unsigned short* __restrict__ A1x, unsigned short* __restrict__ A1y,
    float* __restrict__ P0, float* __restrict__ P1,
    unsigned short* __restrict__ H1bf,
    float* __restrict__ hid0, float* __restrict__ hid1) {
  cooperative_groups::grid_group grid = cooperative_groups::this_grid();
  extern __shared__ unsigned char smem[];
  unsigned short* Wlds = (unsigned short*)smem;            // 16*2048 bf16 = 64KB
  float*          red  = (float*)(smem + 65536);           // 4*1024 f32  = 16KB

  const int bid  = blockIdx.x;
  const int type = bid >> 6;          // 0=L0, 1=L1a, 2=L1b
  const int nt   = bid & 63;
  const int n0   = nt << 4;
  const int tid  = threadIdx.x, lane = tid & 63, w = tid >> 6;

  // ---- preload weight slice into LDS (chunk-XOR swizzle: 2-way max conflict) ----
  const unsigned short* Wsrc = (type == 0) ? B0c : (type == 1) ? B1a : B1b;
  for (int c = tid; c < 4096; c += 256) {                  // 4096 x 16B chunks
    int row = c >> 8;                                      // 0..15
    int cc  = c & 255;
    bf16x8 v = *reinterpret_cast<const bf16x8*>(Wsrc + (size_t)(n0 + row) * 2048 + cc * 8);
    int sc = cc ^ (row & 7);
    *reinterpret_cast<bf16x8*>(&Wlds[row * 2048 + sc * 8]) = v;
  }
  __syncthreads();

  const int kbeg = w << 8;            // per-wave unique-k slice of 256
  const int koff = (lane >> 4) << 3;  // 0,8,16,24
  const int brow = lane & 15;
  const int bswz = brow & 7;

  // epilogue geometry: thread owns outputs o = tid*4 .. tid*4+3 -> m = tid>>2, 4 consecutive n
  const int em   = tid >> 2;
  const int ecol = n0 + ((tid & 3) << 2);

  for (int p = 0; p < 66; ++p) {
    const int pm = p & 1;
    const bool active = (type == 0) ? (p < 64)
                      : (type == 1) ? (p >= 1 && p < 65)
                      : (p >= 2);
    if (active) {
      const unsigned short* Aprev =
          (type == 2) ? (pm ? A1y : A1x) : (pm ? A0y : A0x);

      // prefetch epilogue operands (arrive during MFMA loop)
      float4 pre = {0.f, 0.f, 0.f, 0.f};
      float4 pre2 = {0.f, 0.f, 0.f, 0.f};
      if (type == 0) {
        pre = *reinterpret_cast<const float4*>(U0 + (size_t)p * (BATCH * HID) + em * HID + ecol);
      } else if (type == 2) {
        const float* Pp = pm ? P1 : P0;
        pre  = *reinterpret_cast<const float4*>(Pp + em * HID + ecol);
        pre2 = *reinterpret_cast<const float4*>(b1 + ecol);
      }

      f32x4 acc[4] = {};
#pragma unroll 2
      for (int kc = 0; kc < 256; kc += 32) {
        int colh = kbeg + koff + kc;
        int ch = (colh >> 3) ^ bswz;
        int cl = ((colh + 1024) >> 3) ^ bswz;
        bf16x8 bh = *reinterpret_cast<const bf16x8*>(&Wlds[brow * 2048 + ch * 8]);
        bf16x8 bl = *reinterpret_cast<const bf16x8*>(&Wlds[brow * 2048 + cl * 8]);
#pragma unroll
        for (int i = 0; i < 4; ++i) {
          const unsigned short* ap = Aprev + (size_t)(i * 16 + brow) * 2048 + colh;
          bf16x8 ah = *reinterpret_cast<const bf16x8*>(ap);
          bf16x8 al = *reinterpret_cast<const bf16x8*>(ap + 1024);
          acc[i] = __builtin_amdgcn_mfma_f32_16x16x32_bf16(ah, bh, acc[i], 0, 0, 0);
          acc[i] = __builtin_amdgcn_mfma_f32_16x16x32_bf16(ah, bl, acc[i], 0, 0, 0);
          acc[i] = __builtin_amdgcn_mfma_f32_16x16x32_bf16(al, bh, acc[i], 0, 0, 0);
        }
      }

      // cross-wave reduction in LDS
      const int rrow = (lane >> 4) << 2;
#pragma unroll
      for (int i = 0; i < 4; ++i)
#pragma unroll
        for (int r = 0; r < 4; ++r)
          red[w * 1024 + (i * 16 + rrow + r) * 16 + brow] = acc[i][r];
      __syncthreads();

      {
        const int o = tid * 4;
        float v0 = red[o]        + red[1024 + o]     + red[2048 + o]     + red[3072 + o];
        float v1 = red[o + 1]    + red[1024 + o + 1] + red[2048 + o + 1] + red[3072 + o + 1];
        float v2 = red[o + 2]    + red[1024 + o + 2] + red[2048 + o + 2] + red[3072 + o + 2];
        float v3 = red[o + 3]    + red[1024 + o + 3] + red[2048 + o + 3] + red[3072 + o + 3];
        if (type == 0) {
          float h0v = tanhf(v0 + pre.x), h1v = tanhf(v1 + pre.y);
          float h2v = tanhf(v2 + pre.z), h3v = tanhf(v3 + pre.w);
          unsigned short* An = pm ? A0x : A0y;
          ushort4 hv, lv;
          hv.x = f2bf(h0v); lv.x = f2bf(h0v - bf2f(hv.x));
          hv.y = f2bf(h1v); lv.y = f2bf(h1v - bf2f(hv.y));
          hv.z = f2bf(h2v); lv.z = f2bf(h2v - bf2f(hv.z));
          hv.w = f2bf(h3v); lv.w = f2bf(h3v - bf2f(hv.w));
          *reinterpret_cast<ushort4*>(&An[(size_t)em * 2048 + ecol])        = hv;
          *reinterpret_cast<ushort4*>(&An[(size_t)em * 2048 + 1024 + ecol]) = lv;
          if (p == S_LEN - 1) {
            float4 f; f.x = h0v; f.y = h1v; f.z = h2v; f.w = h3v;
            *reinterpret_cast<float4*>(&hid0[(size_t)em * HID + ecol]) = f;
          }
        } else if (type == 1) {
          float* Pn = pm ? P0 : P1;
          float4 f; f.x = v0; f.y = v1; f.z = v2; f.w = v3;
          *reinterpret_cast<float4*>(&Pn[(size_t)em * HID + ecol]) = f;
        } else {
          float h0v = tanhf(v0 + pre.x + pre2.x), h1v = tanhf(v1 + pre.y + pre2.y);
          float h2v = tanhf(v2 + pre.z + pre2.z), h3v = tanhf(v3 + pre.w + pre2.w);
          unsigned short* An = pm ? A1x : A1y;
          ushort4 hv, lv;
          hv.x = f2bf(h0v); lv.x = f2bf(h0v - bf2f(hv.x));
          hv.y = f2bf(h1v); lv.y = f2bf(h1v - bf2f(hv.y));
          hv.z = f2bf(h2v); lv.z = f2bf(h2v - bf2f(hv.z));
          hv.w = f2bf(h3v); lv.w = f2bf(h3v - bf2f(hv.w));
          *reinterpret_cast<ushort4*>(&An[(size_t)em * 2048 + ecol])        = hv;
          *reinterpret_cast<ushort4*>(&An[(size_t)em * 2048 + 1024 + ecol]) = lv;
          unsigned short* H1t = H1bf + (size_t)(p - 2) * (BATCH * HID);
          *reinterpret_cast<ushort4*>(&H1t[(size_t)em * HID + ecol]) = hv;
          if (p == 65) {
            float4 f; f.x = h0v; f.y = h1v; f.z = h2v; f.w = h3v;
            *reinterpret_cast<float4*>(&hid1[(size_t)em * HID + ecol]) = f;
          }
        }
      }
    }
    grid.sync();
  }
}

// ---------------- launcher ----------------

extern "C" void kernel_launch(void* const* d_in, const int* in_sizes, int n_in,
                              void* d_out, int out_size, void* d_ws, size_t ws_size,
                              hipStream_t stream) {
  (void)in_sizes; (void)n_in; (void)out_size; (void)ws_size;
  const int*   inputs = (const int*)  d_in[0];
  const float* hidden = (const float*)d_in[1];
  const float* emb    = (const float*)d_in[2];
  const float* W0     = (const float*)d_in[3];
  const float* Wh0    = (const float*)d_in[4];
  const float* b0     = (const float*)d_in[5];
  const float* W1     = (const float*)d_in[6];
  const float* Wh1    = (const float*)d_in[7];
  const float* b1     = (const float*)d_in[8];
  const float* Wd     = (const float*)d_in[9];
  const float* bd     = (const float*)d_in[10];

  // scratch inside d_out (consumed before the decoder overwrites logits)
  float*          U0  = (float*)d_out;                                       // 16MB
  unsigned short* Xbf = (unsigned short*)((char*)d_out + (size_t)16777216);  // 8MB

  // persistent scratch in d_ws
  char* ws = (char*)d_ws;
  size_t off = 0;
  auto alloc = [&](size_t bytes) { size_t p = off; off = (off + bytes + 255) & ~(size_t)255; return p; };
  unsigned short* W0bf = (unsigned short*)(ws + alloc((size_t)HID * HID * 2));
  unsigned short* Wdbf = (unsigned short*)(ws + alloc((size_t)VPAD * HID * 2));
  float*          bdp  = (float*)         (ws + alloc((size_t)VPAD * 4));
  unsigned short* B0c  = (unsigned short*)(ws + alloc((size_t)HID * 2048 * 2));
  unsigned short* B1a  = (unsigned short*)(ws + alloc((size_t)HID * 2048 * 2));
  unsigned short* B1b  = (unsigned short*)(ws + alloc((size_t)HID * 2048 * 2));
  unsigned short* H1bf = (unsigned short*)(ws + alloc((size_t)SB * HID * 2));
  unsigned short* A0x  = (unsigned short*)(ws + alloc((size_t)BATCH * 2048 * 2));
  unsigned short* A0y  = (unsigned short*)(ws + alloc((size_t)BATCH * 2048 * 2));
  unsigned short* A1x  = (unsigned short*)(ws + alloc((size_t)BATCH * 2048 * 2));
  unsigned short* A1y  = (unsigned short*)(ws + alloc((size_t)BATCH * 2048 * 2));
  float*          P0   = (float*)         (ws + alloc((size_t)BATCH * HID * 4));
  float*          P1   = (float*)         (ws + alloc((size_t)BATCH * HID * 4));

  float* hid0 = (float*)d_out + (size_t)SBV;            // final h0 [B,H]
  float* hid1 = hid0 + (size_t)BATCH * HID;             // final h1 [B,H]

  // prep
  prep_x <<<SB * HID / 4 / 256, 256, 0, stream>>>(inputs, emb, Xbf);
  prep_w <<<HID * HID / 256,    256, 0, stream>>>(W0, Wh0, W1, Wh1, W0bf, B0c, B1a, B1b);
  prep_wd<<<VPAD * HID / 256,   256, 0, stream>>>(Wd, bd, Wdbf, bdp);
  prep_h <<<BATCH * HID / 256,  256, 0, stream>>>(hidden, A0x, A1x);

  // U0 = X @ W0^T + b0
  gemm_bt_bias<<<dim3(HID / 128, SB / 128), 256, 0, stream>>>(
      Xbf, W0bf, b0, U0, HID, HID, HID);

  // persistent cooperative recurrence (192 blocks, 80KB dynamic LDS -> 2 blocks/CU)
  {
    const unsigned short* cB0c = B0c; const unsigned short* cB1a = B1a;
    const unsigned short* cB1b = B1b; const float* cU0 = U0; const float* cb1 = b1;
    void* args[] = {
        (void*)&cB0c, (void*)&cB1a, (void*)&cB1b, (void*)&cU0, (void*)&cb1,
        (void*)&A0x, (void*)&A0y, (void*)&A1x, (void*)&A1y,
        (void*)&P0, (void*)&P1, (void*)&H1bf, (void*)&hid0, (void*)&hid1};
    hipLaunchCooperativeKernel(reinterpret_cast<const void*>(&rnn_persist),
                               dim3(192), dim3(256), args, 81920, stream);
  }

  // logits = H1 @ Wd^T + bd
  gemm_bt_bias<<<dim3(VPAD / 128, SB / 128), 256, 0, stream>>>(
      H1bf, Wdbf, bdp, (float*)d_out, HID, VOCAB, VOCAB);
}

// Round 5
// 2419.495 us; speedup vs baseline: 1.0586x; 1.0586x over previous
//
#include <hip/hip_runtime.h>
#include <hip/hip_cooperative_groups.h>

// RNN_73701638799445: 2-layer tanh RNN.
// v4: persistent cooperative recurrence, latency fix over v3:
//   - 512 thr/block (8 waves = 2/SIMD), static 128KB LDS, 192 blocks (3 types x 64).
//   - A-state staged to LDS via double-buffered global_load_lds (counted vmcnt(4),
//     raw s_barrier, sched_barrier(0) — m201 idiom; never drain mid-loop).
//   - Source-side XOR swizzle on staged A (linear LDS dest; swizzled global src +
//     swizzled ds_read) to break the 512B-row-stride bank conflict.
//   - Wave = (m-tile, k-half); dual accumulators; 8KB reduce overlays stage buf0.
//   Dataflow/phase windows identical to v3 (proven correct).
// Decoder/U0 GEMM unchanged (XCD n-band swizzle; decoder FETCH 360->88MB verified).

#define S_LEN 64
#define BATCH 64
#define HID   1024
#define VOCAB 10000
#define VPAD  10240           // 80 * 128
#define SB    4096            // S_LEN * BATCH
#define SBV   40960000        // SB * VOCAB

typedef __attribute__((ext_vector_type(4))) float  f32x4;
typedef __attribute__((ext_vector_type(8))) __bf16 bf16x8;

__device__ inline unsigned short f2bf(float x) {
  union { float f; unsigned int u; } v; v.f = x;
  unsigned int r = v.u + 0x7fffu + ((v.u >> 16) & 1u);   // RNE
  return (unsigned short)(r >> 16);
}
__device__ inline float bf2f(unsigned short s) {
  union { unsigned int u; float f; } v; v.u = ((unsigned int)s) << 16;
  return v.f;
}

// ---------------- prep kernels ----------------

__global__ __launch_bounds__(256) void prep_x(
    const int* __restrict__ inputs, const float* __restrict__ emb,
    unsigned short* __restrict__ Xbf) {
  int i = blockIdx.x * 256 + threadIdx.x;       // SB*HID/4 threads
  int row = i >> 8;
  int c4  = (i & 255) * 4;
  int tok = inputs[row];
  const float4 v = *reinterpret_cast<const float4*>(emb + (size_t)tok * HID + c4);
  unsigned short* o = Xbf + (size_t)row * HID + c4;
  o[0] = f2bf(v.x); o[1] = f2bf(v.y); o[2] = f2bf(v.z); o[3] = f2bf(v.w);
}

// W0 -> bf16; Wh0 -> B0c [hi|lo] (row 2048); W1 -> B1a [hi|lo]; Wh1 -> B1b [hi|lo]
__global__ __launch_bounds__(256) void prep_w(
    const float* __restrict__ W0, const float* __restrict__ Wh0,
    const float* __restrict__ W1, const float* __restrict__ Wh1,
    unsigned short* __restrict__ W0bf, unsigned short* __restrict__ B0c,
    unsigned short* __restrict__ B1a, unsigned short* __restrict__ B1b) {
  int id = blockIdx.x * 256 + threadIdx.x;      // HID*HID threads
  int n = id >> 10, k = id & 1023;
  (void)n; (void)k;
  W0bf[id] = f2bf(W0[id]);
  size_t base = (size_t)(id >> 10) * 2048 + (id & 1023);
  {
    float w = Wh0[id];
    unsigned short hi = f2bf(w);
    B0c[base] = hi; B0c[base + 1024] = f2bf(w - bf2f(hi));
  }
  {
    float w = W1[id];
    unsigned short hi = f2bf(w);
    B1a[base] = hi; B1a[base + 1024] = f2bf(w - bf2f(hi));
  }
  {
    float w = Wh1[id];
    unsigned short hi = f2bf(w);
    B1b[base] = hi; B1b[base + 1024] = f2bf(w - bf2f(hi));
  }
}

__global__ __launch_bounds__(256) void prep_wd(
    const float* __restrict__ Wd, const float* __restrict__ bd,
    unsigned short* __restrict__ Wdbf, float* __restrict__ bdp) {
  int id = blockIdx.x * 256 + threadIdx.x;      // VPAD*1024 threads
  int row = id >> 10;
  Wdbf[id] = (row < VOCAB) ? f2bf(Wd[id]) : (unsigned short)0;
  if (id < VPAD) bdp[id] = (id < VOCAB) ? bd[id] : 0.0f;
}

// init state buffers: A0x = [h0hi|h0lo] rows 2048, A1x = [h1hi|h1lo] rows 2048
__global__ __launch_bounds__(256) void prep_h(
    const float* __restrict__ hidden,
    unsigned short* __restrict__ A0x, unsigned short* __restrict__ A1x) {
  int id = blockIdx.x * 256 + threadIdx.x;      // BATCH*HID threads
  int b = id >> 10, n = id & 1023;
  float h0 = hidden[id];
  float h1 = hidden[BATCH * HID + id];
  unsigned short h0hi = f2bf(h0), h1hi = f2bf(h1);
  size_t o = (size_t)b * 2048 + n;
  A0x[o] = h0hi; A0x[o + 1024] = f2bf(h0 - bf2f(h0hi));
  A1x[o] = h1hi; A1x[o + 1024] = f2bf(h1 - bf2f(h1hi));
}

// ---------------- big bf16 GEMM (unchanged) ----------------
__global__ __launch_bounds__(256) void gemm_bt_bias(
    const unsigned short* __restrict__ A, const unsigned short* __restrict__ B,
    const float* __restrict__ bias, float* __restrict__ C,
    int K, int N, int ldc) {
  unsigned bx = blockIdx.x, by = blockIdx.y;
  if ((gridDim.x & 7u) == 0u) {
    const unsigned lin = blockIdx.x + gridDim.x * blockIdx.y;
    const unsigned xpx = gridDim.x >> 3;
    const unsigned xcd = lin & 7u;
    const unsigned idx = lin >> 3;
    bx = xcd * xpx + idx % xpx;
    by = idx / xpx;
  }
  const int m0 = by * 128;
  const int n0 = bx * 128;
  __shared__ __align__(16) unsigned short As[128 * 64];
  __shared__ __align__(16) unsigned short Bs[128 * 64];
  const int tid = threadIdx.x;
  const int lane = tid & 63, w = tid >> 6;
  const int wm = w >> 1, wn = w & 1;
  f32x4 acc[4][4] = {};
  for (int k0 = 0; k0 < K; k0 += 64) {
#pragma unroll
    for (int i = 0; i < 4; ++i) {
      int off = i * 256 + tid;
      int row = off >> 3;
      int c8  = off & 7;
      __builtin_amdgcn_global_load_lds(
          (const __attribute__((address_space(1))) unsigned int*)(const void*)
              (A + (size_t)(m0 + row) * K + k0 + c8 * 8),
          (__attribute__((address_space(3))) unsigned int*)(void*)(As + (size_t)off * 8),
          16, 0, 0);
      __builtin_amdgcn_global_load_lds(
          (const __attribute__((address_space(1))) unsigned int*)(const void*)
              (B + (size_t)(n0 + row) * K + k0 + c8 * 8),
          (__attribute__((address_space(3))) unsigned int*)(void*)(Bs + (size_t)off * 8),
          16, 0, 0);
    }
    __syncthreads();
#pragma unroll
    for (int kk = 0; kk < 64; kk += 32) {
      bf16x8 af[4], bfr[4];
#pragma unroll
      for (int f = 0; f < 4; ++f) {
        int ar = wm * 64 + f * 16 + (lane & 15);
        int ac = kk + (lane >> 4) * 8;
        af[f]  = *reinterpret_cast<const bf16x8*>(&As[ar * 64 + ac]);
        int br = wn * 64 + f * 16 + (lane & 15);
        bfr[f] = *reinterpret_cast<const bf16x8*>(&Bs[br * 64 + ac]);
      }
#pragma unroll
      for (int i = 0; i < 4; ++i)
#pragma unroll
        for (int j = 0; j < 4; ++j)
          acc[i][j] = __builtin_amdgcn_mfma_f32_16x16x32_bf16(af[i], bfr[j], acc[i][j], 0, 0, 0);
    }
    __syncthreads();
  }
  const int rbase = (lane >> 4) * 4;
  const int cbase = lane & 15;
#pragma unroll
  for (int i = 0; i < 4; ++i) {
#pragma unroll
    for (int j = 0; j < 4; ++j) {
      int col = n0 + wn * 64 + j * 16 + cbase;
      if (col < N) {
        float bv = bias[col];
#pragma unroll
        for (int r = 0; r < 4; ++r) {
          int row = m0 + wm * 64 + i * 16 + rbase + r;
          C[(size_t)row * ldc + col] = acc[i][j][r] + bv;
        }
      }
    }
  }
}

// ---------------- persistent recurrence kernel ----------------
// 192 blocks x 512 thr. type=bid>>6: 0=L0, 1=L1a, 2=L1b; nt=bid&63 -> 16 n-cols.
// Wave w: m-tile (w&3), k-half (w>>2). Unique-k 1024 in 8 chunks of 128.
// Stage chunk: [64 rows][hi 128 | lo 128 shorts] = 32KB, double-buffered.
__global__ __launch_bounds__(512, 1) void rnn_persist(
    const unsigned short* __restrict__ B0c,
    const unsigned short* __restrict__ B1a,
    const unsigned short* __restrict__ B1b,
    const float* __restrict__ U0,
    const float* __restrict__ b1,
    unsigned short* __restrict__ A0x, unsigned short* __restrict__ A0y,
    unsigned short* __restrict__ A1x, unsigned short* __restrict__ A1y,
    float* __restrict__ P0, float* __restrict__ P1,
    unsigned short* __restrict__ H1bf,
    float* __restrict__ hid0, float* __restrict__ hid1) {
  cooperative_groups::grid_group grid = cooperative_groups::this_grid();
  __shared__ __align__(16) unsigned short Wlds[16 * 2048];   // 64 KB
  __shared__ __align__(16) unsigned short Ast[2][64 * 256];  // 2 x 32 KB
  float* red = reinterpret_cast<float*>(&Ast[0][0]);         // 8 KB overlay

  const int bid  = blockIdx.x;
  const int type = bid >> 6;
  const int nt   = bid & 63;
  const int n0   = nt << 4;
  const int tid  = threadIdx.x, lane = tid & 63, w = tid >> 6;
  const int mt = w & 3, kh = w >> 2;

  // weight slice preload (16 rows x 2048 shorts, chunk-XOR swizzled)
  const unsigned short* Wsrc = (type == 0) ? B0c : (type == 1) ? B1a : B1b;
  for (int c = tid; c < 4096; c += 512) {
    int row = c >> 8, cc = c & 255;
    bf16x8 v = *reinterpret_cast<const bf16x8*>(Wsrc + (size_t)(n0 + row) * 2048 + cc * 8);
    *reinterpret_cast<bf16x8*>(&Wlds[row * 2048 + (cc ^ (row & 7)) * 8]) = v;
  }
  __syncthreads();

  const int brow = lane & 15;
  const int arow = mt * 16 + brow;
  const int asw  = arow & 7;
  const int bsw  = brow & 7;
  const int kgrp = lane >> 4;                 // 0..3
  // epilogue geometry: thread -> (batch row em, 2 cols cl, cl+1)
  const int em  = tid >> 3;
  const int cl  = (tid & 7) * 2;
  const int emt = em >> 4, eml = em & 15;

  for (int p = 0; p < 66; ++p) {
    const int pm = p & 1;
    const bool active = (type == 0) ? (p < 64)
                      : (type == 1) ? (p >= 1 && p < 65)
                      : (p >= 2);
    if (active) {
      const unsigned short* Aprev = (type == 2) ? (pm ? A1y : A1x) : (pm ? A0y : A0x);

      // epilogue operand prefetch (retires before staging drains; rides vmcnt FIFO)
      float2 preA = make_float2(0.f, 0.f), preB = make_float2(0.f, 0.f);
      if (type == 0) {
        preA = *reinterpret_cast<const float2*>(U0 + (size_t)p * (BATCH * HID) + em * HID + n0 + cl);
      } else if (type == 2) {
        const float* Pp = pm ? P1 : P0;
        preA = *reinterpret_cast<const float2*>(Pp + (size_t)em * HID + n0 + cl);
        preB = *reinterpret_cast<const float2*>(b1 + n0 + cl);
      }

      // stage chunk c into buffer b: LDS linear dest, inverse-swizzled global src
      auto STAGE = [&](int c, int b) {
#pragma unroll
        for (int t = 0; t < 4; ++t) {
          int id  = tid + t * 512;                     // 0..2047
          int row = id >> 5, ci = id & 31;
          int col = ((ci & 15) ^ (row & 7)) * 8 + c * 128 + ((ci >> 4) << 10);
          __builtin_amdgcn_global_load_lds(
              (const __attribute__((address_space(1))) unsigned int*)(const void*)
                  (Aprev + (size_t)row * 2048 + col),
              (__attribute__((address_space(3))) unsigned int*)(void*)(&Ast[b][id * 8]),
              16, 0, 0);
        }
      };

      STAGE(0, 0);
      STAGE(1, 1);
      f32x4 acc0 = {0.f, 0.f, 0.f, 0.f};
      f32x4 acc1 = {0.f, 0.f, 0.f, 0.f};
#pragma unroll
      for (int c = 0; c < 8; ++c) {
        if (c < 7) { asm volatile("s_waitcnt vmcnt(4)" ::: "memory"); }
        else       { asm volatile("s_waitcnt vmcnt(0)" ::: "memory"); }
        __builtin_amdgcn_sched_barrier(0);
        __builtin_amdgcn_s_barrier();
        __builtin_amdgcn_sched_barrier(0);
        const unsigned short* Ab = &Ast[c & 1][0];
        {
          int col8 = kh * 8 + kgrp;                       // kc = 0
          int ch   = ((c * 128 + kh * 64 + kgrp * 8) >> 3) ^ bsw;
          const unsigned short* ap = Ab + arow * 256 + (col8 ^ asw) * 8;
          const unsigned short* bp = Wlds + brow * 2048 + ch * 8;
          bf16x8 ah = *reinterpret_cast<const bf16x8*>(ap);
          bf16x8 al = *reinterpret_cast<const bf16x8*>(ap + 128);
          bf16x8 bh = *reinterpret_cast<const bf16x8*>(bp);
          bf16x8 bl = *reinterpret_cast<const bf16x8*>(bp + 1024);
          acc0 = __builtin_amdgcn_mfma_f32_16x16x32_bf16(ah, bh, acc0, 0, 0, 0);
          acc0 = __builtin_amdgcn_mfma_f32_16x16x32_bf16(ah, bl, acc0, 0, 0, 0);
          acc0 = __builtin_amdgcn_mfma_f32_16x16x32_bf16(al, bh, acc0, 0, 0, 0);
        }
        {
          int col8 = kh * 8 + 4 + kgrp;                   // kc = 1
          int ch   = ((c * 128 + kh * 64 + 32 + kgrp * 8) >> 3) ^ bsw;
          const unsigned short* ap = Ab + arow * 256 + (col8 ^ asw) * 8;
          const unsigned short* bp = Wlds + brow * 2048 + ch * 8;
          bf16x8 ah = *reinterpret_cast<const bf16x8*>(ap);
          bf16x8 al = *reinterpret_cast<const bf16x8*>(ap + 128);
          bf16x8 bh = *reinterpret_cast<const bf16x8*>(bp);
          bf16x8 bl = *reinterpret_cast<const bf16x8*>(bp + 1024);
          acc1 = __builtin_amdgcn_mfma_f32_16x16x32_bf16(ah, bh, acc1, 0, 0, 0);
          acc1 = __builtin_amdgcn_mfma_f32_16x16x32_bf16(ah, bl, acc1, 0, 0, 0);
          acc1 = __builtin_amdgcn_mfma_f32_16x16x32_bf16(al, bh, acc1, 0, 0, 0);
        }
        asm volatile("s_waitcnt lgkmcnt(0)" ::: "memory");
        __builtin_amdgcn_sched_barrier(0);
        __builtin_amdgcn_s_barrier();
        __builtin_amdgcn_sched_barrier(0);
        if (c < 6) STAGE(c + 2, c & 1);
      }

      // cross-(k-half) reduction: wave w dumps its 16x16 tile
      {
        const int rr = (lane >> 4) * 4;
#pragma unroll
        for (int r = 0; r < 4; ++r)
          red[w * 256 + (rr + r) * 16 + brow] = acc0[r] + acc1[r];
      }
      __syncthreads();
      {
        int base = emt * 256 + eml * 16 + cl;
        float v0 = red[base]     + red[base + 1024];
        float v1 = red[base + 1] + red[base + 1025];
        if (type == 0) {
          float h0v = tanhf(v0 + preA.x), h1v = tanhf(v1 + preA.y);
          unsigned short* An = pm ? A0x : A0y;
          ushort2 hv, lv;
          hv.x = f2bf(h0v); lv.x = f2bf(h0v - bf2f(hv.x));
          hv.y = f2bf(h1v); lv.y = f2bf(h1v - bf2f(hv.y));
          *reinterpret_cast<ushort2*>(&An[(size_t)em * 2048 + n0 + cl])        = hv;
          *reinterpret_cast<ushort2*>(&An[(size_t)em * 2048 + 1024 + n0 + cl]) = lv;
          if (p == S_LEN - 1) {
            float2 f; f.x = h0v; f.y = h1v;
            *reinterpret_cast<float2*>(&hid0[(size_t)em * HID + n0 + cl]) = f;
          }
        } else if (type == 1) {
          float* Pn = pm ? P0 : P1;
          float2 f; f.x = v0; f.y = v1;
          *reinterpret_cast<float2*>(&Pn[(size_t)em * HID + n0 + cl]) = f;
        } else {
          float h0v = tanhf(v0 + preA.x + preB.x), h1v = tanhf(v1 + preA.y + preB.y);
          unsigned short* An = pm ? A1x : A1y;
          ushort2 hv, lv;
          hv.x = f2bf(h0v); lv.x = f2bf(h0v - bf2f(hv.x));
          hv.y = f2bf(h1v); lv.y = f2bf(h1v - bf2f(hv.y));
          *reinterpret_cast<ushort2*>(&An[(size_t)em * 2048 + n0 + cl])        = hv;
          *reinterpret_cast<ushort2*>(&An[(size_t)em * 2048 + 1024 + n0 + cl]) = lv;
          unsigned short* H1t = H1bf + (size_t)(p - 2) * (BATCH * HID);
          *reinterpret_cast<ushort2*>(&H1t[(size_t)em * HID + n0 + cl]) = hv;
          if (p == 65) {
            float2 f; f.x = h0v; f.y = h1v;
            *reinterpret_cast<float2*>(&hid1[(size_t)em * HID + n0 + cl]) = f;
          }
        }
      }
    }
    grid.sync();
  }
}

// ---------------- launcher ----------------

extern "C" void kernel_launch(void* const* d_in, const int* in_sizes, int n_in,
                              void* d_out, int out_size, void* d_ws, size_t ws_size,
                              hipStream_t stream) {
  (void)in_sizes; (void)n_in; (void)out_size; (void)ws_size;
  const int*   inputs = (const int*)  d_in[0];
  const float* hidden = (const float*)d_in[1];
  const float* emb    = (const float*)d_in[2];
  const float* W0     = (const float*)d_in[3];
  const float* Wh0    = (const float*)d_in[4];
  const float* b0     = (const float*)d_in[5];
  const float* W1     = (const float*)d_in[6];
  const float* Wh1    = (const float*)d_in[7];
  const float* b1     = (const float*)d_in[8];
  const float* Wd     = (const float*)d_in[9];
  const float* bd     = (const float*)d_in[10];

  // scratch inside d_out (consumed before the decoder overwrites logits)
  float*          U0  = (float*)d_out;                                       // 16MB
  unsigned short* Xbf = (unsigned short*)((char*)d_out + (size_t)16777216);  // 8MB

  // persistent scratch in d_ws
  char* ws = (char*)d_ws;
  size_t off = 0;
  auto alloc = [&](size_t bytes) { size_t p = off; off = (off + bytes + 255) & ~(size_t)255; return p; };
  unsigned short* W0bf = (unsigned short*)(ws + alloc((size_t)HID * HID * 2));
  unsigned short* Wdbf = (unsigned short*)(ws + alloc((size_t)VPAD * HID * 2));
  float*          bdp  = (float*)         (ws + alloc((size_t)VPAD * 4));
  unsigned short* B0c  = (unsigned short*)(ws + alloc((size_t)HID * 2048 * 2));
  unsigned short* B1a  = (unsigned short*)(ws + alloc((size_t)HID * 2048 * 2));
  unsigned short* B1b  = (unsigned short*)(ws + alloc((size_t)HID * 2048 * 2));
  unsigned short* H1bf = (unsigned short*)(ws + alloc((size_t)SB * HID * 2));
  unsigned short* A0x  = (unsigned short*)(ws + alloc((size_t)BATCH * 2048 * 2));
  unsigned short* A0y  = (unsigned short*)(ws + alloc((size_t)BATCH * 2048 * 2));
  unsigned short* A1x  = (unsigned short*)(ws + alloc((size_t)BATCH * 2048 * 2));
  unsigned short* A1y  = (unsigned short*)(ws + alloc((size_t)BATCH * 2048 * 2));
  float*          P0   = (float*)         (ws + alloc((size_t)BATCH * HID * 4));
  float*          P1   = (float*)         (ws + alloc((size_t)BATCH * HID * 4));

  float* hid0 = (float*)d_out + (size_t)SBV;            // final h0 [B,H]
  float* hid1 = hid0 + (size_t)BATCH * HID;             // final h1 [B,H]

  // prep
  prep_x <<<SB * HID / 4 / 256, 256, 0, stream>>>(inputs, emb, Xbf);
  prep_w <<<HID * HID / 256,    256, 0, stream>>>(W0, Wh0, W1, Wh1, W0bf, B0c, B1a, B1b);
  prep_wd<<<VPAD * HID / 256,   256, 0, stream>>>(Wd, bd, Wdbf, bdp);
  prep_h <<<BATCH * HID / 256,  256, 0, stream>>>(hidden, A0x, A1x);

  // U0 = X @ W0^T + b0
  gemm_bt_bias<<<dim3(HID / 128, SB / 128), 256, 0, stream>>>(
      Xbf, W0bf, b0, U0, HID, HID, HID);

  // persistent cooperative recurrence (192 blocks x 512 thr, 128KB static LDS)
  {
    const unsigned short* cB0c = B0c; const unsigned short* cB1a = B1a;
    const unsigned short* cB1b = B1b; const float* cU0 = U0; const float* cb1 = b1;
    void* args[] = {
        (void*)&cB0c, (void*)&cB1a, (void*)&cB1b, (void*)&cU0, (void*)&cb1,
        (void*)&A0x, (void*)&A0y, (void*)&A1x, (void*)&A1y,
        (void*)&P0, (void*)&P1, (void*)&H1bf, (void*)&hid0, (void*)&hid1};
    hipLaunchCooperativeKernel(reinterpret_cast<const void*>(&rnn_persist),
                               dim3(192), dim3(512), args, 0, stream);
  }

  // logits = H1 @ Wd^T + bd
  gemm_bt_bias<<<dim3(VPAD / 128, SB / 128), 256, 0, stream>>>(
      H1bf, Wdbf, bdp, (float*)d_out, HID, VOCAB, VOCAB);
}